// Round 2
// baseline (118.347 us; speedup 1.0000x reference)
//
#include <hip/hip_runtime.h>

#define BB 4
#define IN_DIM 8
#define OUT_DIM 64
#define N_WIN 64
#define N_SEQ 4096
#define N_REAL 6144
#define TT 64                      // t-tile per block (two 32-wide MFMA columns)
#define NTB (N_REAL / TT)          // 96 t-tiles per batch
#define NROW 127                   // valid window rows: tau in [t0-63, t0+63]
#define NPROD 16                   // producer blocks (linear block id 0..15)
#define MAGIC 0x5F3A9C71

typedef __attribute__((ext_vector_type(8)))  short short8;
typedef __attribute__((ext_vector_type(16))) float floatx16;

static __device__ __forceinline__ unsigned short f2bf(float f) {
    union { float f; unsigned int u; } v; v.f = f;
    unsigned int r = v.u + 0x7fffu + ((v.u >> 16) & 1u);   // round-nearest-even
    return (unsigned short)(r >> 16);
}

// ---- Fused kernel: 16 producer blocks repack w[o][i][l] -> w2[l][o][i] (bf16)
//      and post agent-scope flags; all 384 blocks run the scatter+MFMA GEMM,
//      spinning on the flags only right before the first w2 read (overlap).
__global__ __launch_bounds__(256)
void k_fused(const float* __restrict__ x, const float* __restrict__ w,
             const float* __restrict__ bias, const int* __restrict__ sidx,
             unsigned short* __restrict__ w2, int* __restrict__ flags,
             float* __restrict__ out)
{
    __shared__ unsigned short zlds[128 * 8];        // rows tau = t0-63 .. t0+63 (2 KB)
    __shared__ int lo_sh;

    const int tid = threadIdx.x;
    const int bx  = blockIdx.x;                     // 0..95
    const int b   = blockIdx.y;
    const int lin = b * NTB + bx;                   // 0..383

    // ---- producer slice: coalesced loads (lanes sweep l), 16B packed stores
    if (lin < NPROD) {
        const int tg = lin * 256 + tid;             // 0..4095
        const int l = tg & 63, o = tg >> 6;
        const float* wp = w + (size_t)o * (IN_DIM * N_WIN) + l;
        unsigned short v[8];
        #pragma unroll
        for (int i = 0; i < 8; ++i) v[i] = f2bf(wp[(size_t)i * N_WIN]);
        uint4 pk;
        pk.x = v[0] | ((unsigned)v[1] << 16); pk.y = v[2] | ((unsigned)v[3] << 16);
        pk.z = v[4] | ((unsigned)v[5] << 16); pk.w = v[6] | ((unsigned)v[7] << 16);
        *(uint4*)(w2 + ((size_t)(l * OUT_DIM + o)) * 8) = pk;
        __threadfence();                            // make w2 visible at agent scope
        __syncthreads();                            // whole block's stores fenced
        if (tid == 0)
            __hip_atomic_store(&flags[lin], MAGIC, __ATOMIC_RELEASE,
                               __HIP_MEMORY_SCOPE_AGENT);
    }

    // ---- consumer flow (all 384 blocks) ----
    const int t0  = bx * TT;
    const int vlo = t0 - 63;
    const int* idxb = sidx + b * N_SEQ;

    // zero the LDS tile (512 dwords)
    unsigned int* zw = (unsigned int*)zlds;
    zw[tid] = 0u; zw[tid + 256] = 0u;

    // wave 0: 2-round wave-parallel lower_bound(idxb, vlo) — replaces lob[]
    if (tid < 64) {
        int a = idxb[tid * 64];
        unsigned long long m1 = __ballot(a < vlo);
        int cnt = __popcll(m1);
        int coarse = (cnt > 0 ? cnt - 1 : 0) * 64;
        int probe = idxb[coarse + tid];
        unsigned long long m2 = __ballot(probe < vlo);
        if (tid == 0) lo_sh = coarse + __popcll(m2);
    }
    __syncthreads();                                // zeros + lo ready
    const int lo = lo_sh;

    // gather scatter-sources (idx and x loads independent -> overlap)
    const int ig = tid >> 5;                        // input channel 0..7
    const int sl = tid & 31;                        // source slot lane
    const float* xb = x + ((size_t)b * IN_DIM + ig) * N_SEQ;
    int   rarr[4]; float xv[4];
    #pragma unroll
    for (int c = 0; c < 4; ++c) {                   // 4 x 32 slots cover <=127 sources
        int s = lo + c * 32 + sl;
        bool valid = (s < N_SEQ);
        rarr[c] = valid ? (idxb[s] - vlo) : -1;
        xv[c]   = valid ? xb[s] : 0.f;
    }
    #pragma unroll
    for (int c = 0; c < 4; ++c)
        if ((unsigned)rarr[c] < (unsigned)NROW)
            zlds[rarr[c] * 8 + ig] = f2bf(xv[c]);
    __syncthreads();                                // scatter complete

    // spin until all 16 producer flags are posted (usually already done)
    {
        const int fl = tid & 63;
        int cap = 0;
        for (;;) {
            int v = MAGIC;
            if (fl < NPROD)
                v = __hip_atomic_load(&flags[fl], __ATOMIC_ACQUIRE,
                                      __HIP_MEMORY_SCOPE_AGENT);
            if (__ballot(v == MAGIC) == ~0ull) break;
            if (++cap > (1 << 22)) break;           // loud-fail valve, no hang
            __builtin_amdgcn_s_sleep(2);
        }
    }
    __threadfence();                                // acquire side for w2 reads

    // MFMA: 64t x 64o per block, 4 waves (2 o-halves x 2 t-columns)
    const int ln = tid & 31;                        // t / o lane coordinate
    const int lq = (tid >> 5) & 1;                  // k-half within wave
    const int mh = (tid >> 6) & 1;                  // which 32-o half
    const int th = tid >> 7;                        // which 32-t column
    const short8* wv = (const short8*)w2;
    const short8* zv = (const short8*)zlds;
    const int rbase = ln + th * 32 + 63;

    floatx16 acc = {};
    #pragma unroll
    for (int ks = 0; ks < 32; ++ks) {
        const int l = 2 * ks + lq;                  // lag for this k-half
        short8 a  = wv[l * OUT_DIM + mh * 32 + ln]; // L1/L2-hot after first blocks
        short8 bz = zv[rbase - l];                  // LDS b128, conflict-free
        acc = __builtin_amdgcn_mfma_f32_32x32x16_bf16(a, bz, acc, 0, 0, 0);
    }

    // C/D layout (m74/m101): col=lane&31 -> t, row=(p&3)+8*(p>>2)+4*(lane>>5) -> o
    #pragma unroll
    for (int p = 0; p < 16; ++p) {
        int o = (p & 3) + 8 * (p >> 2) + 4 * lq + mh * 32;
        out[((size_t)b * OUT_DIM + o) * N_REAL + t0 + th * 32 + ln] = acc[p] + bias[o];
    }
}

extern "C" void kernel_launch(void* const* d_in, const int* in_sizes, int n_in,
                              void* d_out, int out_size, void* d_ws, size_t ws_size,
                              hipStream_t stream) {
    const float* px = nullptr; const float* pw = nullptr;
    const float* pb = nullptr; const int* ps = nullptr;

    for (int i = 0; i < n_in; ++i) {
        switch (in_sizes[i]) {
            case BB * IN_DIM * N_SEQ:        px = (const float*)d_in[i]; break; // x
            case OUT_DIM * IN_DIM * N_WIN:   pw = (const float*)d_in[i]; break; // weight
            case OUT_DIM:                    pb = (const float*)d_in[i]; break; // bias
            case BB * N_SEQ:                 ps = (const int*)d_in[i];   break; // sourceIdx
            default: break;
        }
    }
    if (!px || !pw || !pb || !ps) {
        px = (const float*)d_in[0]; pw = (const float*)d_in[1];
        pb = (const float*)d_in[2]; ps = (const int*)d_in[3];
    }

    unsigned short* w2 = (unsigned short*)d_ws;                  // 64 KB
    int* flags = (int*)((char*)d_ws + 64 * 1024);                // 64 B
    float* out = (float*)d_out;

    k_fused<<<dim3(NTB, BB), 256, 0, stream>>>(px, pw, pb, ps, w2, flags, out);
}

// Round 3
// 71.219 us; speedup vs baseline: 1.6617x; 1.6617x over previous
//
#include <hip/hip_runtime.h>

#define BB 4
#define IN_DIM 8
#define OUT_DIM 64
#define N_WIN 64
#define N_SEQ 4096
#define N_REAL 6144
#define TT 64                      // t-tile per block (two 32-wide MFMA columns)
#define NTB (N_REAL / TT)          // 96 t-tiles per batch
#define NROW 127                   // valid window rows: tau in [t0-63, t0+63]

typedef __attribute__((ext_vector_type(8)))  short short8;
typedef __attribute__((ext_vector_type(16))) float floatx16;

static __device__ __forceinline__ unsigned short f2bf(float f) {
    union { float f; unsigned int u; } v; v.f = f;
    unsigned int r = v.u + 0x7fffu + ((v.u >> 16) & 1u);   // round-nearest-even
    return (unsigned short)(r >> 16);
}

// ---- K1: pack weights w[o][i][l] -> w2[l][o][i] (bf16), coalesced loads
//          (lanes sweep l) + all 384 window lower-bounds in parallel.
__global__ __launch_bounds__(64)
void k_prep(const float* __restrict__ w, const int* __restrict__ sidx,
            unsigned short* __restrict__ w2, int* __restrict__ lob)
{
    const int tg = blockIdx.x * 64 + threadIdx.x;   // 0..4095, 64 blocks on 64 CUs
    const int l = tg & 63, o = tg >> 6;             // lane = l -> coalesced loads
    const float* wp = w + (size_t)o * (IN_DIM * N_WIN) + l;
    unsigned short v[8];
    #pragma unroll
    for (int i = 0; i < 8; ++i) v[i] = f2bf(wp[(size_t)i * N_WIN]);
    uint4 pk;
    pk.x = v[0] | ((unsigned)v[1] << 16); pk.y = v[2] | ((unsigned)v[3] << 16);
    pk.z = v[4] | ((unsigned)v[5] << 16); pk.w = v[6] | ((unsigned)v[7] << 16);
    *(uint4*)(w2 + ((size_t)(l * OUT_DIM + o)) * 8) = pk;

    if (tg < BB * NTB) {                            // one thread per (b, t-tile)
        const int b  = tg / NTB, bx = tg - b * NTB;
        const int vlo = bx * TT - 63;
        const int* idxb = sidx + b * N_SEQ;
        int lo = 0, hi = N_SEQ;
        while (lo < hi) { int m = (lo + hi) >> 1; if (idxb[m] < vlo) lo = m + 1; else hi = m; }
        lob[tg] = lo;
    }
}

// ---- K2: MFMA GEMM, 64 t x 64 o per block, 4 waves (2 o-halves x 2 t-columns).
//          ALL 32 A-fragments prefetched into registers before the barriers:
//          L2 latency hides under zero/scatter; MFMA loop is ds_read+mfma only.
__global__ __launch_bounds__(256)
void k_gemm(const float* __restrict__ x, const unsigned short* __restrict__ w2,
            const float* __restrict__ bias, const int* __restrict__ sidx,
            const int* __restrict__ lob, float* __restrict__ out)
{
    __shared__ unsigned short zlds[128 * 8];        // rows tau = t0-63 .. t0+63 (2 KB)

    const int tid = threadIdx.x;
    const int bx  = blockIdx.x;                     // 0..95
    const int b   = blockIdx.y;
    const int t0  = bx * TT;
    const int vlo = t0 - 63;
    const int lo  = lob[b * NTB + bx];              // uniform -> scalar load

    // zero the LDS tile (512 dwords)
    unsigned int* zw = (unsigned int*)zlds;
    zw[tid] = 0u; zw[tid + 256] = 0u;

    // issue scatter-source loads NOW (dependent idx->x chain starts earliest)
    const int ig = tid >> 5;                        // input channel 0..7
    const int sl = tid & 31;                        // source slot lane
    const int* idxb = sidx + b * N_SEQ;
    const float* xb = x + ((size_t)b * IN_DIM + ig) * N_SEQ;
    int   rarr[4]; float xv[4];
    #pragma unroll
    for (int c = 0; c < 4; ++c) {                   // 4 x 32 slots cover <=127 sources
        int s = lo + c * 32 + sl;
        bool valid = (s < N_SEQ);
        rarr[c] = valid ? (idxb[s] - vlo) : -1;
        xv[c]   = valid ? xb[s] : 0.f;
    }

    // FULL A-fragment prefetch (32 x b128 = 128 VGPR); independent L2 loads
    // pipeline behind the x-gather and complete under the barriers below.
    const int ln = tid & 31;                        // t / o lane coordinate
    const int lq = (tid >> 5) & 1;                  // k-half within wave
    const int mh = (tid >> 6) & 1;                  // which 32-o half
    const int th = tid >> 7;                        // which 32-t column
    const short8* wv = (const short8*)w2;
    short8 apre[32];
    #pragma unroll
    for (int k = 0; k < 32; ++k)
        apre[k] = wv[(2 * k + lq) * OUT_DIM + mh * 32 + ln];

    __syncthreads();                                // zeros complete
    #pragma unroll
    for (int c = 0; c < 4; ++c)
        if ((unsigned)rarr[c] < (unsigned)NROW)
            zlds[rarr[c] * 8 + ig] = f2bf(xv[c]);
    __syncthreads();                                // scatter complete

    // bias preload (epilogue has no dependent loads)
    float bv[16];
    #pragma unroll
    for (int p = 0; p < 16; ++p)
        bv[p] = bias[(p & 3) + 8 * (p >> 2) + 4 * lq + mh * 32];

    floatx16 acc = {};
    const short8* zv = (const short8*)zlds;
    const int rbase = ln + th * 32 + 63;
    #pragma unroll
    for (int ks = 0; ks < 32; ++ks) {
        short8 bz = zv[rbase - (2 * ks + lq)];      // LDS b128, conflict-free
        acc = __builtin_amdgcn_mfma_f32_32x32x16_bf16(apre[ks], bz, acc, 0, 0, 0);
    }

    // C/D layout (m74/m101): col=lane&31 -> t, row=(p&3)+8*(p>>2)+4*(lane>>5) -> o
    #pragma unroll
    for (int p = 0; p < 16; ++p) {
        int o = (p & 3) + 8 * (p >> 2) + 4 * lq + mh * 32;
        out[((size_t)b * OUT_DIM + o) * N_REAL + t0 + th * 32 + ln] = acc[p] + bv[p];
    }
}

extern "C" void kernel_launch(void* const* d_in, const int* in_sizes, int n_in,
                              void* d_out, int out_size, void* d_ws, size_t ws_size,
                              hipStream_t stream) {
    const float* px = nullptr; const float* pw = nullptr;
    const float* pb = nullptr; const int* ps = nullptr;

    for (int i = 0; i < n_in; ++i) {
        switch (in_sizes[i]) {
            case BB * IN_DIM * N_SEQ:        px = (const float*)d_in[i]; break; // x
            case OUT_DIM * IN_DIM * N_WIN:   pw = (const float*)d_in[i]; break; // weight
            case OUT_DIM:                    pb = (const float*)d_in[i]; break; // bias
            case BB * N_SEQ:                 ps = (const int*)d_in[i];   break; // sourceIdx
            default: break;
        }
    }
    if (!px || !pw || !pb || !ps) {
        px = (const float*)d_in[0]; pw = (const float*)d_in[1];
        pb = (const float*)d_in[2]; ps = (const int*)d_in[3];
    }

    unsigned short* w2 = (unsigned short*)d_ws;                  // 64 KB
    int* lob = (int*)((char*)d_ws + 64 * 1024);                  // 1.5 KB
    float* out = (float*)d_out;

    k_prep<<<64, 64, 0, stream>>>(pw, ps, w2, lob);
    k_gemm<<<dim3(NTB, BB), 256, 0, stream>>>(px, w2, pb, ps, lob, out);
}